// Round 4
// baseline (1358.078 us; speedup 1.0000x reference)
//
#include <hip/hip_runtime.h>

// K-means assignment via split-fp16 MFMA GEMM + fused argmin.
// d2 = x2 + c2 - 2*x.cT ; x = hi+lo (fp16 each), dot = hh + hl + lh on
// mfma_f32_16x16x32_f16 (fp32 accum). Error ~1e-6 < fp32 sum-order noise.
// N=131072, K=2048, D=512.
//
// R4 (vs 890/859us): 256x128 tile, 8 waves (4x2), TRIPLE-buffered LDS,
// single-barrier register-pipelined K-loop:
//   iter t: { stage(t+3) -> buf[(t+3)%3];  ds_read frags(t+1) from
//   buf[(t+1)%3] into the alternate reg set;  MFMA x48 on frags(t);
//   lgkmcnt(0); vmcnt(6) [counted -- this iter's 6 GLLs stay in flight];
//   s_barrier }.
//   - frag prefetch 1 tile ahead (2 register sets, static indices) lets the
//     compiler overlap ds_read latency under MFMA via register deps (R3's
//     per-phase barriers did the opposite and regressed).
//   - staging 3 tiles ahead + 3rd buffer => end-of-iter wait is COUNTED,
//     never a vmcnt(0) drain; each stage has ~2 iterations (~2000cy) of
//     cover >= 900cy HBM latency.
//   - BM=256 halves the C re-read traffic (512 passes instead of 1024).
// Carried: XOR-swizzled LDS (bank conflicts = 0), setprio around MFMA.

#define N_PTS 131072
#define K_CL  2048
#define D_DIM 512
#define BM 256
#define BN 128
#define BK 32
#define THREADS 512
#define NKT (K_CL / BN)    // 16 K-tiles
#define NDT (D_DIM / BK)   // 16 D-steps
#define NT  (NKT * NDT)    // 256 total iterations
#define XPLANE (BM * BK)   // 8192 f16 = 16 KB
#define CPLANE (BN * BK)   // 4096 f16 = 8 KB

typedef _Float16 half8  __attribute__((ext_vector_type(8)));
typedef _Float16 half4v __attribute__((ext_vector_type(4)));
typedef float    floatx4 __attribute__((ext_vector_type(4)));

// async global->LDS, 16B per lane; LDS dest = wave-uniform base + lane*16,
// global source address is PER-LANE (carries the swizzle).
#define GLL(g, l) __builtin_amdgcn_global_load_lds( \
    (__attribute__((address_space(1))) void*)(g),   \
    (__attribute__((address_space(3))) void*)(l), 16, 0, 0)

// ---- c2 norms: one wave per row ----
__global__ void row_norms_kernel(const float* __restrict__ A,
                                 float* __restrict__ out, int rows) {
    int gid  = blockIdx.x * blockDim.x + threadIdx.x;
    int wave = gid >> 6;
    int lane = gid & 63;
    if (wave >= rows) return;
    const float4* a = (const float4*)(A + (size_t)wave * D_DIM);
    float4 p = a[lane];
    float4 q = a[lane + 64];
    float s = p.x*p.x + p.y*p.y + p.z*p.z + p.w*p.w
            + q.x*q.x + q.y*q.y + q.z*q.z + q.w*q.w;
    #pragma unroll
    for (int off = 32; off > 0; off >>= 1) s += __shfl_down(s, off, 64);
    if (lane == 0) out[wave] = s;
}

// ---- fp32 -> (hi,lo) fp16 planes ----
__global__ void conv_f16x2_kernel(const float* __restrict__ src,
                                  _Float16* __restrict__ hi,
                                  _Float16* __restrict__ lo, int n4) {
    int i = blockIdx.x * blockDim.x + threadIdx.x;
    if (i >= n4) return;
    float4 v = ((const float4*)src)[i];
    half4v h, l;
    h.x = (_Float16)v.x; h.y = (_Float16)v.y;
    h.z = (_Float16)v.z; h.w = (_Float16)v.w;
    l.x = (_Float16)(v.x - (float)h.x);
    l.y = (_Float16)(v.y - (float)h.y);
    l.z = (_Float16)(v.z - (float)h.z);
    l.w = (_Float16)(v.w - (float)h.w);
    *(half4v*)(hi + (size_t)i * 4) = h;
    *(half4v*)(lo + (size_t)i * 4) = l;
}

// ---- main: 256x128 block over all K, split-fp16 MFMA, fused argmin ----
// LDS tile swizzle: logical element [row][k], 16B chunk j = k/8 (0..3),
// stored at chunk position j ^ ((row>>1)&3). Staging pre-swizzles the
// GLOBAL source chunk (global_load_lds writes linearly); reads use swizzled
// chunk position. Fragment ds_read_b128 => 2-way bank access (free).
template<bool XPRE, bool CPRE>
__global__ __launch_bounds__(THREADS, 2)
void kmeans_mfma(const float* __restrict__ X, const float* __restrict__ C,
                 const _Float16* __restrict__ Xhi, const _Float16* __restrict__ Xlo,
                 const _Float16* __restrict__ Chi, const _Float16* __restrict__ Clo,
                 const float* __restrict__ c2g, int* __restrict__ out) {
    constexpr bool ASYNC = XPRE && CPRE;   // pure global_load_lds staging

    // triple-buffered unpadded [row][BK] f16 tiles (64B rows; linear dest
    // required by global_load_lds). 3*48KB + 9KB = 153 KB.
    __shared__ __align__(16) _Float16 sXh[3][XPLANE], sXl[3][XPLANE];
    __shared__ __align__(16) _Float16 sCh[3][CPLANE], sCl[3][CPLANE];
    __shared__ float c2s[K_CL];      // 8 KB
    __shared__ float x2s[BM];        // 1 KB

    const int tid  = threadIdx.x;
    const int lane = tid & 63;
    const int w    = tid >> 6;       // wave id 0..7
    const int wti  = w >> 1;         // row quarter (0..3)
    const int wtj  = w & 1;          // col half (0..1)
    const int q    = lane >> 4;      // quad
    const int m16  = lane & 15;
    const int rowBase = blockIdx.x * BM;

    // swizzle constants
    const int jsrc = (((lane & 3) ^ ((lane >> 3) & 3)) * 8);  // staging: src chunk for lane
    const int swq8 = ((q ^ ((m16 >> 1) & 3)) * 8);            // read: stored position of logical chunk q

    // c2 into LDS
    if (CPRE) {
        for (int i = tid; i < K_CL / 4; i += THREADS)
            ((float4*)c2s)[i] = ((const float4*)c2g)[i];
    } else {
        for (int k = tid; k < K_CL; k += THREADS) {
            const float4* cp = (const float4*)(C + (size_t)k * D_DIM);
            float s0 = 0.f, s1 = 0.f;
            for (int j = 0; j < D_DIM / 4; j += 2) {
                float4 a = cp[j], b = cp[j + 1];
                s0 += a.x*a.x + a.y*a.y + a.z*a.z + a.w*a.w;
                s1 += b.x*b.x + b.y*b.y + b.z*b.z + b.w*b.w;
            }
            c2s[k] = s0 + s1;
        }
    }
    // x2 into LDS (2 threads per row; partials staged in sXh scratch)
    {
        int r = tid & (BM - 1), h = tid >> 8;
        const float4* xp = (const float4*)(X + (size_t)(rowBase + r) * D_DIM + h * 256);
        float s0 = 0.f, s1 = 0.f;
        for (int j = 0; j < 64; j += 2) {
            float4 a = xp[j], b = xp[j + 1];
            s0 += a.x*a.x + a.y*a.y + a.z*a.z + a.w*a.w;
            s1 += b.x*b.x + b.y*b.y + b.z*b.z + b.w*b.w;
        }
        ((float*)sXh)[tid] = s0 + s1;
    }
    __syncthreads();
    if (tid < BM) x2s[tid] = ((float*)sXh)[tid] + ((float*)sXh)[tid + BM];
    __syncthreads();   // scratch reads done before staging overwrites buf0

    // on-the-fly staging mapping (fallback paths)
    const int s_c4 = tid & 7;    // float4-col within BK
    const int s_r0 = tid >> 3;   // row 0..63

    // stage tile t into buffer b. ASYNC: 6 GLLs/wave (X: 2 chunks x hi/lo,
    // C: 1 chunk x hi/lo), each chunk = 16 rows x 64 B.
    auto stage = [&](int t, int b) {
        const int dtl = t & (NDT - 1);
        const int ktl = t >> 4;              // NDT == 16
        const int d0  = dtl * BK;
        const int k0l = ktl * BN;
        _Float16* dXh = sXh[b]; _Float16* dXl = sXl[b];
        _Float16* dCh = sCh[b]; _Float16* dCl = sCl[b];
        if constexpr (XPRE) {
            #pragma unroll
            for (int s = 0; s < 2; ++s) {
                const int cc = w * 2 + s;                // 16-row chunk 0..15
                const int r  = cc * 16 + (lane >> 2);
                const size_t go = (size_t)(rowBase + r) * D_DIM + d0 + jsrc;
                GLL(Xhi + go, &dXh[cc * 512]);
                GLL(Xlo + go, &dXl[cc * 512]);
            }
        } else {
            #pragma unroll
            for (int p = 0; p < 4; ++p) {
                const int r = s_r0 + p * 64;
                float4 v = *(const float4*)&X[(size_t)(rowBase + r) * D_DIM + d0 + s_c4 * 4];
                half4v h, l;
                h.x = (_Float16)v.x; h.y = (_Float16)v.y;
                h.z = (_Float16)v.z; h.w = (_Float16)v.w;
                l.x = (_Float16)(v.x - (float)h.x);
                l.y = (_Float16)(v.y - (float)h.y);
                l.z = (_Float16)(v.z - (float)h.z);
                l.w = (_Float16)(v.w - (float)h.w);
                const int off = r * BK + (((s_c4 >> 1) ^ ((r >> 1) & 3)) * 8) + (s_c4 & 1) * 4;
                *(half4v*)&dXh[off] = h;
                *(half4v*)&dXl[off] = l;
            }
        }
        if constexpr (CPRE) {
            const int r = w * 16 + (lane >> 2);          // chunk w, rows 16w..
            const size_t go = (size_t)(k0l + r) * D_DIM + d0 + jsrc;
            GLL(Chi + go, &dCh[w * 512]);
            GLL(Clo + go, &dCl[w * 512]);
        } else {
            #pragma unroll
            for (int p = 0; p < 2; ++p) {
                const int r = s_r0 + p * 64;
                float4 v = *(const float4*)&C[(size_t)(k0l + r) * D_DIM + d0 + s_c4 * 4];
                half4v h, l;
                h.x = (_Float16)v.x; h.y = (_Float16)v.y;
                h.z = (_Float16)v.z; h.w = (_Float16)v.w;
                l.x = (_Float16)(v.x - (float)h.x);
                l.y = (_Float16)(v.y - (float)h.y);
                l.z = (_Float16)(v.z - (float)h.z);
                l.w = (_Float16)(v.w - (float)h.w);
                const int off = r * BK + (((s_c4 >> 1) ^ ((r >> 1) & 3)) * 8) + (s_c4 & 1) * 4;
                *(half4v*)&dCh[off] = h;
                *(half4v*)&dCl[off] = l;
            }
        }
    };

    // two register fragment sets (static first index only -- rule #20)
    half8 fah[2][4], fal[2][4], fbh[2][4], fbl[2][4];
    floatx4 acc[4][4];

    #define READ_FRAGS(B_, S_) do {                                        \
        const _Float16* xh_ = sXh[B_]; const _Float16* xl_ = sXl[B_];      \
        const _Float16* ch_ = sCh[B_]; const _Float16* cl_ = sCl[B_];      \
        _Pragma("unroll")                                                  \
        for (int ti_ = 0; ti_ < 4; ++ti_) {                                \
            const int row_ = wti * 64 + ti_ * 16 + m16;                    \
            fah[S_][ti_] = *(const half8*)&xh_[row_ * BK + swq8];          \
            fal[S_][ti_] = *(const half8*)&xl_[row_ * BK + swq8];          \
        }                                                                  \
        _Pragma("unroll")                                                  \
        for (int tj_ = 0; tj_ < 4; ++tj_) {                                \
            const int col_ = wtj * 64 + tj_ * 16 + m16;                    \
            fbh[S_][tj_] = *(const half8*)&ch_[col_ * BK + swq8];          \
            fbl[S_][tj_] = *(const half8*)&cl_[col_ * BK + swq8];          \
        }                                                                  \
    } while (0)

    #define MFMA48(S_) do {                                                \
        __builtin_amdgcn_s_setprio(1);                                     \
        _Pragma("unroll")                                                  \
        for (int tj_ = 0; tj_ < 4; ++tj_)                                  \
            _Pragma("unroll")                                              \
            for (int ti_ = 0; ti_ < 4; ++ti_) {                            \
                floatx4 a_ = acc[ti_][tj_];                                \
                a_ = __builtin_amdgcn_mfma_f32_16x16x32_f16(fah[S_][ti_], fbh[S_][tj_], a_, 0, 0, 0); \
                a_ = __builtin_amdgcn_mfma_f32_16x16x32_f16(fah[S_][ti_], fbl[S_][tj_], a_, 0, 0, 0); \
                a_ = __builtin_amdgcn_mfma_f32_16x16x32_f16(fal[S_][ti_], fbh[S_][tj_], a_, 0, 0, 0); \
                acc[ti_][tj_] = a_;                                        \
            }                                                              \
        __builtin_amdgcn_s_setprio(0);                                     \
    } while (0)

    // one iteration of the pipelined loop (ASYNC only).
    // invariants at entry: frags(t) in set CUR_; tile t+1 complete in
    // buf[(t+1)%3]; stage(t+2) issued last iter (lands before vmcnt(6)).
    #define ITER(T_, CUR_, NXT_) do {                                       \
        if ((T_) + 3 < NT) stage((T_) + 3, bS);                             \
        if ((T_) + 1 < NT) READ_FRAGS(bR, NXT_);                            \
        MFMA48(CUR_);                                                       \
        asm volatile("s_waitcnt lgkmcnt(0)" ::: "memory");                  \
        if ((T_) + 3 < NT) asm volatile("s_waitcnt vmcnt(6)" ::: "memory"); \
        else               asm volatile("s_waitcnt vmcnt(0)" ::: "memory"); \
        __builtin_amdgcn_s_barrier();                                       \
        bR = (bR == 2) ? 0 : bR + 1;                                        \
        bS = (bS == 2) ? 0 : bS + 1;                                        \
    } while (0)

    float bestV[4][4];
    int   bestI[4][4];
    #pragma unroll
    for (int ti = 0; ti < 4; ++ti)
        #pragma unroll
        for (int r = 0; r < 4; ++r) { bestV[ti][r] = 3.4e38f; bestI[ti][r] = 0; }

    int bR = 1, bS = 0;
    if constexpr (ASYNC) {
        // prologue: tiles 0,1,2 staged; frags(0) -> set 0.
        stage(0, 0); stage(1, 1); stage(2, 2);
        asm volatile("s_waitcnt vmcnt(6)" ::: "memory");  // tiles 0,1 landed (self)
        __builtin_amdgcn_s_barrier();                     // ... across all waves
        READ_FRAGS(0, 0);
        asm volatile("s_waitcnt lgkmcnt(0)" ::: "memory");
        __builtin_amdgcn_s_barrier();                     // buf0 reads done -> iter0 may restage it
    }

    #pragma unroll 1
    for (int kt = 0; kt < NKT; ++kt) {
        const int k0 = kt * BN;
        #pragma unroll
        for (int ti = 0; ti < 4; ++ti)
            #pragma unroll
            for (int tj = 0; tj < 4; ++tj) acc[ti][tj] = (floatx4){0.f, 0.f, 0.f, 0.f};

        if constexpr (ASYNC) {
            #pragma unroll 1
            for (int dt = 0; dt < NDT; dt += 2) {
                const int t = kt * NDT + dt;
                ITER(t,     0, 1);
                ITER(t + 1, 1, 0);
            }
        } else {
            #pragma unroll 1
            for (int dt = 0; dt < NDT; ++dt) {
                const int t = kt * NDT + dt;
                __syncthreads();           // previous tile reads done
                stage(t, 0);
                __syncthreads();           // tile staged (drains vm+lgkm)
                READ_FRAGS(0, 0);
                MFMA48(0);
            }
        }

        // fused argmin epilogue. D layout: col=lane&15, row=quad*4+reg.
        // cols ascend (kt, then tj) per (ti,reg) + strict '<'  => first-occurrence.
        #pragma unroll
        for (int tj = 0; tj < 4; ++tj) {
            int col = k0 + wtj * 64 + tj * 16 + m16;
            float cv = c2s[col];
            #pragma unroll
            for (int ti = 0; ti < 4; ++ti)
                #pragma unroll
                for (int r = 0; r < 4; ++r) {
                    float s = x2s[wti * 64 + ti * 16 + q * 4 + r] + cv;
                    float v = s - 2.0f * acc[ti][tj][r];
                    if (v < bestV[ti][r]) { bestV[ti][r] = v; bestI[ti][r] = col; }
                }
        }
    }
    #undef ITER
    #undef MFMA48
    #undef READ_FRAGS

    // cross-lane reduce over the 16 lanes sharing each row (lexicographic)
    #pragma unroll
    for (int ti = 0; ti < 4; ++ti)
        #pragma unroll
        for (int r = 0; r < 4; ++r) {
            float v = bestV[ti][r]; int ix = bestI[ti][r];
            #pragma unroll
            for (int off = 1; off < 16; off <<= 1) {
                float ov = __shfl_xor(v, off, 64);
                int   oi = __shfl_xor(ix, off, 64);
                if (ov < v || (ov == v && oi < ix)) { v = ov; ix = oi; }
            }
            bestV[ti][r] = v; bestI[ti][r] = ix;
        }

    __syncthreads();                   // tiles no longer needed; reuse as scratch
    float* rv  = (float*)sXh;          // [256][2]
    int*   rix = (int*)sCh;            // [256][2]
    if (m16 == 0) {
        #pragma unroll
        for (int ti = 0; ti < 4; ++ti)
            #pragma unroll
            for (int r = 0; r < 4; ++r) {
                int rloc = wti * 64 + ti * 16 + q * 4 + r;
                rv[rloc * 2 + wtj]  = bestV[ti][r];
                rix[rloc * 2 + wtj] = bestI[ti][r];
            }
    }
    __syncthreads();
    if (tid < BM) {
        float v0 = rv[tid * 2], v1 = rv[tid * 2 + 1];
        int   i0 = rix[tid * 2], i1 = rix[tid * 2 + 1];
        out[rowBase + tid] = (v1 < v0 || (v1 == v0 && i1 < i0)) ? i1 : i0;
    }
}

extern "C" void kernel_launch(void* const* d_in, const int* in_sizes, int n_in,
                              void* d_out, int out_size, void* d_ws, size_t ws_size,
                              hipStream_t stream) {
    const float* X = (const float*)d_in[0];   // [N, D]
    const float* C = (const float*)d_in[1];   // [K, D]
    int* out = (int*)d_out;

    char* ws = (char*)d_ws;
    const size_t c2_off  = 0;
    const size_t chi_off = (size_t)K_CL * 4;                       // 8 KB
    const size_t clo_off = chi_off + (size_t)K_CL * D_DIM * 2;     // +2 MB
    const size_t xhi_off = clo_off + (size_t)K_CL * D_DIM * 2;     // +2 MB
    const size_t xlo_off = xhi_off + (size_t)N_PTS * D_DIM * 2;    // +128 MB
    const size_t need_C    = xhi_off;                              // ~4.2 MB
    const size_t need_full = xlo_off + (size_t)N_PTS * D_DIM * 2;  // ~272.6 MB

    if (ws_size >= need_full) {
        float*    c2  = (float*)(ws + c2_off);
        _Float16* Chi = (_Float16*)(ws + chi_off);
        _Float16* Clo = (_Float16*)(ws + clo_off);
        _Float16* Xhi = (_Float16*)(ws + xhi_off);
        _Float16* Xlo = (_Float16*)(ws + xlo_off);
        row_norms_kernel<<<(K_CL * 64) / 256, 256, 0, stream>>>(C, c2, K_CL);
        conv_f16x2_kernel<<<(K_CL * D_DIM / 4) / 256, 256, 0, stream>>>(
            C, Chi, Clo, K_CL * D_DIM / 4);
        conv_f16x2_kernel<<<(N_PTS * D_DIM / 4 + 255) / 256, 256, 0, stream>>>(
            X, Xhi, Xlo, N_PTS * D_DIM / 4);
        kmeans_mfma<true, true><<<N_PTS / BM, THREADS, 0, stream>>>(
            X, C, Xhi, Xlo, Chi, Clo, c2, out);
    } else if (ws_size >= need_C) {
        float*    c2  = (float*)(ws + c2_off);
        _Float16* Chi = (_Float16*)(ws + chi_off);
        _Float16* Clo = (_Float16*)(ws + clo_off);
        row_norms_kernel<<<(K_CL * 64) / 256, 256, 0, stream>>>(C, c2, K_CL);
        conv_f16x2_kernel<<<(K_CL * D_DIM / 4) / 256, 256, 0, stream>>>(
            C, Chi, Clo, K_CL * D_DIM / 4);
        kmeans_mfma<false, true><<<N_PTS / BM, THREADS, 0, stream>>>(
            X, C, nullptr, nullptr, Chi, Clo, c2, out);
    } else {
        kmeans_mfma<false, false><<<N_PTS / BM, THREADS, 0, stream>>>(
            X, C, nullptr, nullptr, nullptr, nullptr, nullptr, out);
    }
}